// Round 16
// baseline (198.857 us; speedup 1.0000x reference)
//
#include <hip/hip_runtime.h>

#define DMODEL 1024
#define NHEAD  16
#define HWID   64
#define FFDIM  4096
#define NBATCH 2
#define SEQT   2048
#define NTOK   4096   // NBATCH*SEQT
#define QKLD   3072   // qkv row stride

using bf8    = __attribute__((ext_vector_type(8))) short;
using f32x4  = __attribute__((ext_vector_type(4))) float;
using f32x16 = __attribute__((ext_vector_type(16))) float;

__device__ inline short to_bf16(float f) {
  unsigned u = __float_as_uint(f);
  return (short)((u + 0x7fffu + ((u >> 16) & 1u)) >> 16);
}
__device__ inline float from_bf16(short s) {
  return __uint_as_float(((unsigned)(unsigned short)s) << 16);
}
__device__ inline float exp2_fast(float x) {
  float r;
  asm("v_exp_f32 %0, %1" : "=v"(r) : "v"(x));
  return r;
}
__device__ inline unsigned cvt_pk_bf16(float lo, float hi) {
  unsigned r;
  asm("v_cvt_pk_bf16_f32 %0, %1, %2" : "=v"(r) : "v"(lo), "v"(hi));
  return r;
}
__device__ inline void lds_load16(const void* g, void* l) {
  __builtin_amdgcn_global_load_lds(
      (const __attribute__((address_space(1))) void*)g,
      (__attribute__((address_space(3))) void*)l, 16, 0, 0);
}

// ---- prep: weight cvt (blocks 0..11263) + LN1 (blocks 11264..15359) ----
__global__ __launch_bounds__(256)
void prep_kernel(const float* __restrict__ Wq, const float* __restrict__ Wk,
                 const float* __restrict__ Wv, const float* __restrict__ W1,
                 const float* __restrict__ W2, short* __restrict__ wqkv,
                 short* __restrict__ w1b, short* __restrict__ w2b,
                 const float* __restrict__ x, const float* __restrict__ g1,
                 const float* __restrict__ b1, short* __restrict__ xn) {
  __shared__ float red[8];
  if (blockIdx.x < 11264) {
    int i = blockIdx.x * 256 + threadIdx.x;   // float4 index, total 2883584
    const float* src;
    short* dst;
    if (i < 1048576)      { src = W1; dst = w1b; }
    else if (i < 2097152) { src = W2; dst = w2b;            i -= 1048576; }
    else if (i < 2359296) { src = Wq; dst = wqkv;           i -= 2097152; }
    else if (i < 2621440) { src = Wk; dst = wqkv + 1048576; i -= 2359296; }
    else                  { src = Wv; dst = wqkv + 2097152; i -= 2621440; }
    float4 v = ((const float4*)src)[i];
    short4 o;
    o.x = to_bf16(v.x); o.y = to_bf16(v.y);
    o.z = to_bf16(v.z); o.w = to_bf16(v.w);
    ((short4*)dst)[i] = o;
  } else {
    const int row = blockIdx.x - 11264;
    const int t = threadIdx.x;
    const float4 v = ((const float4*)(x + (long)row * DMODEL))[t];
    float s  = v.x + v.y + v.z + v.w;
    float s2 = v.x * v.x + v.y * v.y + v.z * v.z + v.w * v.w;
#pragma unroll
    for (int m = 1; m < 64; m <<= 1) {
      s  += __shfl_xor(s, m);
      s2 += __shfl_xor(s2, m);
    }
    if ((t & 63) == 0) { red[t >> 6] = s; red[4 + (t >> 6)] = s2; }
    __syncthreads();
    s  = red[0] + red[1] + red[2] + red[3];
    s2 = red[4] + red[5] + red[6] + red[7];
    const float mu = s * (1.f / DMODEL);
    const float rs = rsqrtf(s2 * (1.f / DMODEL) - mu * mu + 1e-5f);
    const float4 gv = ((const float4*)g1)[t];
    const float4 bv = ((const float4*)b1)[t];
    short4 o;
    o.x = to_bf16((v.x - mu) * rs * gv.x + bv.x);
    o.y = to_bf16((v.y - mu) * rs * gv.y + bv.y);
    o.z = to_bf16((v.z - mu) * rs * gv.z + bv.z);
    o.w = to_bf16((v.w - mu) * rs * gv.w + bv.w);
    ((short4*)(xn + (long)row * DMODEL))[t] = o;
  }
}

// ---------------- LayerNorm (f32 in -> bf16 out) ----------------
__global__ __launch_bounds__(256)
void ln_kernel(const float* __restrict__ x, const float* __restrict__ g,
               const float* __restrict__ b, short* __restrict__ out) {
  const int row = blockIdx.x;
  const int t = threadIdx.x;
  const float4 v = ((const float4*)(x + (long)row * DMODEL))[t];
  float s  = v.x + v.y + v.z + v.w;
  float s2 = v.x * v.x + v.y * v.y + v.z * v.z + v.w * v.w;
#pragma unroll
  for (int m = 1; m < 64; m <<= 1) {
    s  += __shfl_xor(s, m);
    s2 += __shfl_xor(s2, m);
  }
  __shared__ float red[8];
  if ((t & 63) == 0) { red[t >> 6] = s; red[4 + (t >> 6)] = s2; }
  __syncthreads();
  s  = red[0] + red[1] + red[2] + red[3];
  s2 = red[4] + red[5] + red[6] + red[7];
  const float mu = s * (1.f / DMODEL);
  const float rs = rsqrtf(s2 * (1.f / DMODEL) - mu * mu + 1e-5f);
  const float4 gv = ((const float4*)g)[t];
  const float4 bv = ((const float4*)b)[t];
  short4 o;
  o.x = to_bf16((v.x - mu) * rs * gv.x + bv.x);
  o.y = to_bf16((v.y - mu) * rs * gv.y + bv.y);
  o.z = to_bf16((v.z - mu) * rs * gv.z + bv.z);
  o.w = to_bf16((v.w - mu) * rs * gv.w + bv.w);
  ((short4*)(out + (long)row * DMODEL))[t] = o;
}

// ---- 8-phase 256x256 NT GEMM (R11 structure, best measured).
// EPI 0: bf16 store; 1: SiLU bf16; 2: bf16 parts + z*zstride.
template <int EPI>
__global__ __launch_bounds__(512, 2)
void gemm256(const short* __restrict__ A, const short* __restrict__ Bw,
             void* __restrict__ Cout, int N, int lda, int ldb, int Kslice,
             long zstride) {
  __shared__ short lds[2][2][16384];
  const int tid = threadIdx.x;
  const int wid = tid >> 6, lane = tid & 63;
  const int l15 = lane & 15, l4 = lane >> 4;
  const int wm = wid >> 2, wn = wid & 3;

  const int gx = gridDim.x, nwg = gx * gridDim.y;
  const int wg = blockIdx.y * gx + blockIdx.x;
  const int sw = (wg & 7) * (nwg >> 3) + (wg >> 3);
  const int sx = gx >> 2;
  const int st = sw >> 4, w16 = sw & 15;
  const long bm = (long)((st / sx) * 4 + (w16 >> 2)) * 256;
  const long bn = (long)((st % sx) * 4 + (w16 & 3)) * 256;
  const long kofs = (long)blockIdx.z * Kslice;
  const int NT = Kslice >> 6;

  long arow[2], brow[2];
  int  sgel[2], dofs[2];
#pragma unroll
  for (int l = 0; l < 2; ++l) {
    const int g = l * 512 + tid;
    const int row = g >> 2;
    sgel[l] = ((g & 3) ^ ((row >> 1) & 3)) * 8;
    dofs[l] = g * 16;
    arow[l] = (bm + row) * (long)lda + kofs;
    brow[l] = (bn + row) * (long)ldb + kofs;
  }
  auto stage_half = [&](int h) {
    if (h >= (NT << 2)) return;
    const int th = h >> 2, hi = h & 3, buf = th & 1;
    const int ks = hi >> 1, isA = hi & 1;
    char* db = (char*)&lds[buf][isA ? 0 : 1][0] + ks * 16384;
    const long kb = (long)th * 64 + ks * 32;
#pragma unroll
    for (int l = 0; l < 2; ++l) {
      const short* src = (isA ? A + arow[l] : Bw + brow[l]) + kb + sgel[l];
      lds_load16(src, db + dofs[l]);
    }
  };

  const int xsw = (l4 ^ ((l15 >> 1) & 3)) << 4;
  const int aofs = (wm * 128 + l15) * 64 + xsw;
  const int bofs = (wn * 64 + l15) * 64 + xsw;

  f32x4 acc[8][4] = {};
  bf8 fa[4], fa2[4], fb[4];

#define PH_MID                                             \
  __builtin_amdgcn_s_barrier();                            \
  __builtin_amdgcn_s_setprio(1);
#define PH_END                                             \
  __builtin_amdgcn_s_setprio(0);                           \
  __builtin_amdgcn_s_barrier();                            \
  asm volatile("" ::: "memory");

#pragma unroll
  for (int h = 0; h < 7; ++h) stage_half(h);
  asm volatile("s_waitcnt vmcnt(6)" ::: "memory");
  __builtin_amdgcn_s_barrier();
  asm volatile("" ::: "memory");

  for (int u = 0; u < NT; ++u) {
    const int buf = u & 1;
    const char* pa = (const char*)&lds[buf][0][0];
    const char* pb = (const char*)&lds[buf][1][0];
#pragma unroll
    for (int m = 0; m < 4; ++m) fa[m] = *(const bf8*)(pa + aofs + m * 1024);
#pragma unroll
    for (int n = 0; n < 4; ++n) fb[n] = *(const bf8*)(pb + bofs + n * 1024);
    stage_half(4 * u + 7);
    PH_MID
#pragma unroll
    for (int m = 0; m < 4; ++m)
#pragma unroll
      for (int n = 0; n < 4; ++n)
        acc[m][n] = __builtin_amdgcn_mfma_f32_16x16x32_bf16(fa[m], fb[n], acc[m][n], 0, 0, 0);
    PH_END
#pragma unroll
    for (int m = 0; m < 4; ++m) fa2[m] = *(const bf8*)(pa + aofs + (4 + m) * 1024);
    stage_half(4 * u + 8);
    PH_MID
#pragma unroll
    for (int m = 0; m < 4; ++m)
#pragma unroll
      for (int n = 0; n < 4; ++n)
        acc[4 + m][n] = __builtin_amdgcn_mfma_f32_16x16x32_bf16(fa2[m], fb[n], acc[4 + m][n], 0, 0, 0);
    PH_END
#pragma unroll
    for (int m = 0; m < 4; ++m) fa[m] = *(const bf8*)(pa + 16384 + aofs + m * 1024);
#pragma unroll
    for (int n = 0; n < 4; ++n) fb[n] = *(const bf8*)(pb + 16384 + bofs + n * 1024);
    stage_half(4 * u + 9);
    PH_MID
#pragma unroll
    for (int m = 0; m < 4; ++m)
#pragma unroll
      for (int n = 0; n < 4; ++n)
        acc[m][n] = __builtin_amdgcn_mfma_f32_16x16x32_bf16(fa[m], fb[n], acc[m][n], 0, 0, 0);
    PH_END
#pragma unroll
    for (int m = 0; m < 4; ++m) fa2[m] = *(const bf8*)(pa + 16384 + aofs + (4 + m) * 1024);
    stage_half(4 * u + 10);
    if (u <= NT - 3)      asm volatile("s_waitcnt vmcnt(6)" ::: "memory");
    else if (u == NT - 2) asm volatile("s_waitcnt vmcnt(0)" ::: "memory");
    PH_MID
#pragma unroll
    for (int m = 0; m < 4; ++m)
#pragma unroll
      for (int n = 0; n < 4; ++n)
        acc[4 + m][n] = __builtin_amdgcn_mfma_f32_16x16x32_bf16(fa2[m], fb[n], acc[4 + m][n], 0, 0, 0);
    PH_END
  }
#undef PH_MID
#undef PH_END

  // ---------- epilogue ----------
#pragma unroll
  for (int mg = 0; mg < 8; ++mg)
#pragma unroll
    for (int n = 0; n < 4; ++n) {
      const long col = bn + wn * 64 + n * 16 + l15;
#pragma unroll
      for (int r = 0; r < 4; ++r) {
        const long row = bm + wm * 128 + mg * 16 + l4 * 4 + r;
        float v = acc[mg][n][r];
        if (EPI == 0) {
          ((short*)Cout)[row * N + col] = to_bf16(v);
        } else if (EPI == 1) {
          ((short*)Cout)[row * N + col] = to_bf16(v / (1.f + __expf(-v)));
        } else {
          ((short*)Cout)[blockIdx.z * zstride + row * N + col] = to_bf16(v);
        }
      }
    }
}

// ---------------- K pack + V pack, one launch ----------------
__global__ __launch_bounds__(256)
void pack_kv(const short* __restrict__ qkv, short* __restrict__ Kp,
             short* __restrict__ Vp) {
  __shared__ short tile[64][72];
  const int bx = blockIdx.x, bh = blockIdx.y;
  const int b = bh >> 4, h = bh & 15;
  const int t = threadIdx.x;
  if (bx < 64) {
    const int g = bx;
    const int row = t >> 3, cc = t & 7, c = cc >> 1, hi = cc & 1;
    const bf8 v = *(const bf8*)&qkv[(long)(b * SEQT + g * 32 + row) * QKLD +
                                    1024 + h * HWID + c * 16 + hi * 8];
    *(bf8*)&Kp[(((long)bh * 256 + g * 4 + c) * 64 + hi * 32 + row) * 8] = v;
  } else {
    const int tc = bx - 64;
    {
      const int r = t >> 2, c = (t & 3) * 16;
      const long src = (long)(b * SEQT + tc * 64 + r) * QKLD + 2048 + h * HWID + c;
      *(bf8*)&tile[r][c]     = *(const bf8*)&qkv[src];
      *(bf8*)&tile[r][c + 8] = *(const bf8*)&qkv[src + 8];
    }
    __syncthreads();
    const int dg = t >> 7, ch = (t >> 5) & 3, row = t & 31;
#pragma unroll
    for (int hi = 0; hi < 2; ++hi) {
      short o[8];
#pragma unroll
      for (int j = 0; j < 8; ++j) o[j] = tile[ch * 16 + hi * 8 + j][dg * 32 + row];
      *(bf8*)&Vp[(((long)bh * 256 + dg * 128 + tc * 4 + ch) * 64 + hi * 32 + row) * 8] =
          *(bf8*)o;
    }
  }
}

// ---- Flash attention: 512 balanced blocks x 4 waves; per-wave code = R11 ----
// Block (bh, i): waves handle qtiles {i, 63-i, 31-i, 32+i} -> 130 iters/block.
__global__ __launch_bounds__(256, 2)
void attn_kernel(const short* __restrict__ qkv, const short* __restrict__ Kp,
                 const short* __restrict__ Vp, const short* __restrict__ xn,
                 float* __restrict__ att) {
  __shared__ float Os[4][32 * 68];
  const int L = blockIdx.x;                       // 0..511
  const int bh = (L & 7) * 4 + ((L >> 3) & 3);    // XCD-friendly bh spread
  const int i = L >> 5;                           // 0..15
  const int w = threadIdx.x >> 6;
  const int qtile = (w == 0) ? i : (w == 1) ? 63 - i : (w == 2) ? 31 - i : 32 + i;
  const int b = bh >> 4, h = bh & 15;
  const int q0 = qtile * 32;
  const int lane = threadIdx.x & 63;
  const int l31 = lane & 31, hi = lane >> 5;
  const long tokbase = (long)b * SEQT;

  bf8 qf[4];
  {
    const short* qrow = qkv + (tokbase + q0 + l31) * QKLD + h * HWID + hi * 8;
#pragma unroll
    for (int c = 0; c < 4; ++c) qf[c] = *(const bf8*)(qrow + c * 16);
  }

  const float slope2 = exp2f(-0.5f * (float)(h + 1)) * 1.44269504f;
  const float sc2 = 0.125f * 1.44269504f;
  float arr[16];
#pragma unroll
  for (int r = 0; r < 16; ++r) arr[r] = slope2 * (float)((r & 3) + 8 * (r >> 2));
  const float hofs = slope2 * 4.f * (float)hi;
  const float qabs = (float)(q0 + l31);

  float m2 = -1e30f, lsum = 0.f;
  f32x16 acc0 = {}, acc1 = {};
  const int ktm = q0 >> 6;
  const bf8* kfb = (const bf8*)Kp + (long)bh * 16384 + lane;
  const bf8* vfb = (const bf8*)Vp + (long)bh * 16384 + lane;

  bf8 kc[8], kn[8], vc[8];
#pragma unroll
  for (int c = 0; c < 4; ++c) {
    kc[c]     = kfb[c * 64];
    kc[4 + c] = kfb[256 + c * 64];
  }

#pragma unroll 2
  for (int kt = 0; kt <= ktm; ++kt) {
    const int k0 = kt * 64;
    const long vb = (long)kt * 256;
#pragma unroll
    for (int ch = 0; ch < 4; ++ch) {
      vc[ch]     = vfb[vb + ch * 64];
      vc[4 + ch] = vfb[8192 + vb + ch * 64];
    }
    const long nb = (long)(kt < ktm ? kt + 1 : kt) * 512;
#pragma unroll
    for (int c = 0; c < 4; ++c) {
      kn[c]     = kfb[nb + c * 64];
      kn[4 + c] = kfb[nb + 256 + c * 64];
    }
    f32x16 s0 = {}, s1 = {};
#pragma unroll
    for (int c = 0; c < 4; ++c) {
      s0 = __builtin_amdgcn_mfma_f32_32x32x16_bf16(kc[c], qf[c], s0, 0, 0, 0);
      s1 = __builtin_amdgcn_mfma_f32_32x32x16_bf16(kc[4 + c], qf[c], s1, 0, 0, 0);
    }
    const float base = slope2 * ((float)k0 - qabs) + hofs;
    float s[32];
#pragma unroll
    for (int r = 0; r < 16; ++r) {
      s[r]      = fmaf(s0[r], sc2, base + arr[r]);
      s[16 + r] = fmaf(s1[r], sc2, base + arr[r] + slope2 * 32.f);
    }
    if (kt == ktm) {
      const int qi = q0 + l31;
#pragma unroll
      for (int r = 0; r < 16; ++r) {
        const int krel = (r & 3) + 8 * (r >> 2) + 4 * hi;
        if (k0 + krel > qi)      s[r]      = -1e30f;
        if (k0 + 32 + krel > qi) s[16 + r] = -1e30f;
      }
    }
    float ma = s[0], mb = s[1], mc = s[2], md = s[3];
#pragma unroll
    for (int i2 = 4; i2 < 32; i2 += 4) {
      ma = fmaxf(ma, s[i2]); mb = fmaxf(mb, s[i2 + 1]);
      mc = fmaxf(mc, s[i2 + 2]); md = fmaxf(md, s[i2 + 3]);
    }
    float pm = fmaxf(fmaxf(ma, mb), fmaxf(mc, md));
    pm = fmaxf(pm, __shfl_xor(pm, 32));
    if (!__all(pm - m2 <= 11.0f)) {
      const float nm = fmaxf(m2, pm);
      const float alpha = exp2_fast(m2 - nm);
      m2 = nm;
      lsum *= alpha;
      acc0 *= alpha;
      acc1 *= alpha;
    }
    float p[32];
#pragma unroll
    for (int i2 = 0; i2 < 32; ++i2) p[i2] = exp2_fast(s[i2] - m2);
    float sa = p[0], sb = p[1], sc = p[2], sd = p[3];
#pragma unroll
    for (int i2 = 4; i2 < 32; i2 += 4) {
      sa += p[i2]; sb += p[i2 + 1]; sc += p[i2 + 2]; sd += p[i2 + 3];
    }
    float rs = (sa + sb) + (sc + sd);
    rs += __shfl_xor(rs, 32);
    lsum += rs;
    unsigned cpk[16];
#pragma unroll
    for (int g = 0; g < 8; ++g) {
      cpk[g]     = cvt_pk_bf16(p[2 * g], p[2 * g + 1]);
      cpk[8 + g] = cvt_pk_bf16(p[16 + 2 * g], p[16 + 2 * g + 1]);
    }
    bf8 pb[4];
#pragma unroll
    for (int ch = 0; ch < 4; ++ch) {
      const int cb = (ch >> 1) * 8 + (ch & 1) * 4;
      unsigned u0 = cpk[cb + 0], u2 = cpk[cb + 2];
      unsigned u1 = cpk[cb + 1], u3 = cpk[cb + 3];
      asm("v_permlane32_swap_b32 %0, %1" : "+v"(u0), "+v"(u2));
      asm("v_permlane32_swap_b32 %0, %1" : "+v"(u1), "+v"(u3));
      union { unsigned u[4]; bf8 v; } f;
      f.u[0] = u0; f.u[1] = u1; f.u[2] = u2; f.u[3] = u3;
      pb[ch] = f.v;
    }
#pragma unroll
    for (int ch = 0; ch < 4; ++ch) {
      acc0 = __builtin_amdgcn_mfma_f32_32x32x16_bf16(vc[ch], pb[ch], acc0, 0, 0, 0);
      acc1 = __builtin_amdgcn_mfma_f32_32x32x16_bf16(vc[4 + ch], pb[ch], acc1, 0, 0, 0);
    }
#pragma unroll
    for (int i2 = 0; i2 < 8; ++i2) kc[i2] = kn[i2];
  }

  // per-wave private Os slab; within-wave LDS ordering is compiler-tracked
  float* os = &Os[w][0];
  const float rl = 1.f / lsum;
#pragma unroll
  for (int r = 0; r < 16; ++r) {
    const int d0 = (r & 3) + 8 * (r >> 2) + 4 * hi;
    os[l31 * 68 + d0]      = acc0[r] * rl;
    os[l31 * 68 + 32 + d0] = acc1[r] * rl;
  }
#pragma unroll
  for (int it = 0; it < 8; ++it) {
    const int idx = it * 64 + lane;
    const int row = idx >> 4, c4 = idx & 15;
    const float4 ov = *(const float4*)&os[row * 68 + c4 * 4];
    const long gbase = (tokbase + q0 + row) * DMODEL + h * HWID + c4 * 4;
    const short4 xv = *(const short4*)&xn[gbase];
    float4 o;
    o.x = ov.x + from_bf16(xv.x);
    o.y = ov.y + from_bf16(xv.y);
    o.z = ov.z + from_bf16(xv.z);
    o.w = ov.w + from_bf16(xv.w);
    *(float4*)&att[gbase] = o;
  }
}

// ---------------- combine: d_out += sum of 4 split-K bf16 partials ----------
__global__ __launch_bounds__(256)
void combine_kernel(const short* __restrict__ p, float* __restrict__ dout, int n4) {
  int i = blockIdx.x * 256 + threadIdx.x;
  if (i < n4) {
    float4 a = ((const float4*)dout)[i];
    short4 b0 = ((const short4*)(p))[i];
    short4 b1 = ((const short4*)(p + 4194304))[i];
    short4 b2 = ((const short4*)(p + 8388608))[i];
    short4 b3 = ((const short4*)(p + 12582912))[i];
    a.x += (from_bf16(b0.x) + from_bf16(b1.x)) + (from_bf16(b2.x) + from_bf16(b3.x));
    a.y += (from_bf16(b0.y) + from_bf16(b1.y)) + (from_bf16(b2.y) + from_bf16(b3.y));
    a.z += (from_bf16(b0.z) + from_bf16(b1.z)) + (from_bf16(b2.z) + from_bf16(b3.z));
    a.w += (from_bf16(b0.w) + from_bf16(b1.w)) + (from_bf16(b2.w) + from_bf16(b3.w));
    ((float4*)dout)[i] = a;
  }
}

// ---------------- launcher ----------------
extern "C" void kernel_launch(void* const* d_in, const int* in_sizes, int n_in,
                              void* d_out, int out_size, void* d_ws, size_t ws_size,
                              hipStream_t stream) {
  (void)in_sizes; (void)n_in; (void)out_size; (void)ws_size;
  const float* x  = (const float*)d_in[0];
  const float* Wq = (const float*)d_in[1];
  const float* Wk = (const float*)d_in[2];
  const float* Wv = (const float*)d_in[3];
  const float* W1 = (const float*)d_in[4];
  const float* W2 = (const float*)d_in[5];
  const float* g1 = (const float*)d_in[6];
  const float* b1 = (const float*)d_in[7];
  const float* g2 = (const float*)d_in[8];
  const float* b2 = (const float*)d_in[9];

  char* ws = (char*)d_ws;
  const size_t MB = 1024 * 1024;
  short* wqkv_b = (short*)(ws + 0);        // 6 MB [3072][1024]
  short* w1_b   = (short*)(ws + 6  * MB);  // 8 MB
  short* w2_b   = (short*)(ws + 14 * MB);  // 8 MB
  short* xn     = (short*)(ws + 22 * MB);  // 8 MB [NTOK][D]
  short* qkv    = (short*)(ws + 30 * MB);  // 24 MB [NTOK][3072]
  short* m1     = (short*)(ws + 22 * MB);  // 32 MB (aliases xn+qkv, dead after attn)
  short* Kp     = (short*)(ws + 54 * MB);  // 8 MB packed K frags (dead after attn)
  short* Vp     = (short*)(ws + 62 * MB);  // 8 MB packed V frags (dead after attn)
  short* hb     = (short*)(ws + 70 * MB);  // 8 MB (dead after mlp1)
  short* parts  = (short*)(ws + 54 * MB);  // 32 MB bf16 (aliases Kp/Vp/hb)
  float* att    = (float*)d_out;           // att lives in d_out (combine residual)

  // fused weight-convert + LN1
  prep_kernel<<<15360, 256, 0, stream>>>(Wq, Wk, Wv, W1, W2, wqkv_b, w1_b, w2_b,
                                         x, g1, b1, xn);

  // fused QKV: [NTOK][3072]
  gemm256<0><<<dim3(12, 16), 512, 0, stream>>>(xn, wqkv_b, qkv, QKLD, DMODEL, DMODEL,
                                               DMODEL, 0);
  pack_kv<<<dim3(96, 32), 256, 0, stream>>>(qkv, Kp, Vp);

  attn_kernel<<<512, 256, 0, stream>>>(qkv, Kp, Vp, xn, att);

  ln_kernel<<<NTOK, 256, 0, stream>>>(att, g2, b2, hb);

  // MLP1: m1 = silu(hb * w1^T)
  gemm256<1><<<dim3(16, 16), 512, 0, stream>>>(hb, w1_b, m1, FFDIM, DMODEL, DMODEL,
                                               DMODEL, 0);
  // MLP2 split-K=4 into bf16 parts, then combine with att residual (in d_out)
  gemm256<2><<<dim3(4, 16, 4), 512, 0, stream>>>(m1, w2_b, parts, DMODEL, FFDIM, FFDIM,
                                                 1024, (long)NTOK * DMODEL);
  combine_kernel<<<4096, 256, 0, stream>>>(parts, (float*)d_out, 1048576);
}

// Round 17
// 194.591 us; speedup vs baseline: 1.0219x; 1.0219x over previous
//
#include <hip/hip_runtime.h>

#define DMODEL 1024
#define NHEAD  16
#define HWID   64
#define FFDIM  4096
#define NBATCH 2
#define SEQT   2048
#define NTOK   4096   // NBATCH*SEQT
#define QKLD   3072   // qkv row stride

using bf8    = __attribute__((ext_vector_type(8))) short;
using f32x4  = __attribute__((ext_vector_type(4))) float;
using f32x16 = __attribute__((ext_vector_type(16))) float;

__device__ inline short to_bf16(float f) {
  unsigned u = __float_as_uint(f);
  return (short)((u + 0x7fffu + ((u >> 16) & 1u)) >> 16);
}
__device__ inline float from_bf16(short s) {
  return __uint_as_float(((unsigned)(unsigned short)s) << 16);
}
__device__ inline float exp2_fast(float x) {
  float r;
  asm("v_exp_f32 %0, %1" : "=v"(r) : "v"(x));
  return r;
}
__device__ inline unsigned cvt_pk_bf16(float lo, float hi) {
  unsigned r;
  asm("v_cvt_pk_bf16_f32 %0, %1, %2" : "=v"(r) : "v"(lo), "v"(hi));
  return r;
}
__device__ inline void lds_load16(const void* g, void* l) {
  __builtin_amdgcn_global_load_lds(
      (const __attribute__((address_space(1))) void*)g,
      (__attribute__((address_space(3))) void*)l, 16, 0, 0);
}

// ---- prep: weight cvt (blocks 0..11263) + LN1 (blocks 11264..15359) ----
__global__ __launch_bounds__(256)
void prep_kernel(const float* __restrict__ Wq, const float* __restrict__ Wk,
                 const float* __restrict__ Wv, const float* __restrict__ W1,
                 const float* __restrict__ W2, short* __restrict__ wqkv,
                 short* __restrict__ w1b, short* __restrict__ w2b,
                 const float* __restrict__ x, const float* __restrict__ g1,
                 const float* __restrict__ b1, short* __restrict__ xn) {
  __shared__ float red[8];
  if (blockIdx.x < 11264) {
    int i = blockIdx.x * 256 + threadIdx.x;   // float4 index, total 2883584
    const float* src;
    short* dst;
    if (i < 1048576)      { src = W1; dst = w1b; }
    else if (i < 2097152) { src = W2; dst = w2b;            i -= 1048576; }
    else if (i < 2359296) { src = Wq; dst = wqkv;           i -= 2097152; }
    else if (i < 2621440) { src = Wk; dst = wqkv + 1048576; i -= 2359296; }
    else                  { src = Wv; dst = wqkv + 2097152; i -= 2621440; }
    float4 v = ((const float4*)src)[i];
    short4 o;
    o.x = to_bf16(v.x); o.y = to_bf16(v.y);
    o.z = to_bf16(v.z); o.w = to_bf16(v.w);
    ((short4*)dst)[i] = o;
  } else {
    const int row = blockIdx.x - 11264;
    const int t = threadIdx.x;
    const float4 v = ((const float4*)(x + (long)row * DMODEL))[t];
    float s  = v.x + v.y + v.z + v.w;
    float s2 = v.x * v.x + v.y * v.y + v.z * v.z + v.w * v.w;
#pragma unroll
    for (int m = 1; m < 64; m <<= 1) {
      s  += __shfl_xor(s, m);
      s2 += __shfl_xor(s2, m);
    }
    if ((t & 63) == 0) { red[t >> 6] = s; red[4 + (t >> 6)] = s2; }
    __syncthreads();
    s  = red[0] + red[1] + red[2] + red[3];
    s2 = red[4] + red[5] + red[6] + red[7];
    const float mu = s * (1.f / DMODEL);
    const float rs = rsqrtf(s2 * (1.f / DMODEL) - mu * mu + 1e-5f);
    const float4 gv = ((const float4*)g1)[t];
    const float4 bv = ((const float4*)b1)[t];
    short4 o;
    o.x = to_bf16((v.x - mu) * rs * gv.x + bv.x);
    o.y = to_bf16((v.y - mu) * rs * gv.y + bv.y);
    o.z = to_bf16((v.z - mu) * rs * gv.z + bv.z);
    o.w = to_bf16((v.w - mu) * rs * gv.w + bv.w);
    ((short4*)(xn + (long)row * DMODEL))[t] = o;
  }
}

// ---------------- LayerNorm (f32 in -> bf16 out) ----------------
__global__ __launch_bounds__(256)
void ln_kernel(const float* __restrict__ x, const float* __restrict__ g,
               const float* __restrict__ b, short* __restrict__ out) {
  const int row = blockIdx.x;
  const int t = threadIdx.x;
  const float4 v = ((const float4*)(x + (long)row * DMODEL))[t];
  float s  = v.x + v.y + v.z + v.w;
  float s2 = v.x * v.x + v.y * v.y + v.z * v.z + v.w * v.w;
#pragma unroll
  for (int m = 1; m < 64; m <<= 1) {
    s  += __shfl_xor(s, m);
    s2 += __shfl_xor(s2, m);
  }
  __shared__ float red[8];
  if ((t & 63) == 0) { red[t >> 6] = s; red[4 + (t >> 6)] = s2; }
  __syncthreads();
  s  = red[0] + red[1] + red[2] + red[3];
  s2 = red[4] + red[5] + red[6] + red[7];
  const float mu = s * (1.f / DMODEL);
  const float rs = rsqrtf(s2 * (1.f / DMODEL) - mu * mu + 1e-5f);
  const float4 gv = ((const float4*)g)[t];
  const float4 bv = ((const float4*)b)[t];
  short4 o;
  o.x = to_bf16((v.x - mu) * rs * gv.x + bv.x);
  o.y = to_bf16((v.y - mu) * rs * gv.y + bv.y);
  o.z = to_bf16((v.z - mu) * rs * gv.z + bv.z);
  o.w = to_bf16((v.w - mu) * rs * gv.w + bv.w);
  ((short4*)(out + (long)row * DMODEL))[t] = o;
}

// ---- 8-phase 256xBN NT GEMM (R11 structure), BN = NF*64 (NF=3 or 4).
// EPI 0: bf16 store; 1: SiLU bf16; 2: bf16 parts + z*zstride.
template <int EPI, int NF>
__global__ __launch_bounds__(512, 2)
void gemm256(const short* __restrict__ A, const short* __restrict__ Bw,
             void* __restrict__ Cout, int N, int lda, int ldb, int Kslice,
             long zstride) {
  __shared__ short lds[2][2][16384];
  const int tid = threadIdx.x;
  const int wid = tid >> 6, lane = tid & 63;
  const int l15 = lane & 15, l4 = lane >> 4;
  const int wm = wid >> 2, wn = wid & 3;
  const int BROWS = NF * 64;                 // B tile rows

  const int gx = gridDim.x, nwg = gx * gridDim.y;
  const int wg = blockIdx.y * gx + blockIdx.x;
  const int sw = (wg & 7) * (nwg >> 3) + (wg >> 3);
  const int sx = gx >> 2;
  const int st = sw >> 4, w16 = sw & 15;
  const long bm = (long)((st / sx) * 4 + (w16 >> 2)) * 256;
  const long bn = (long)((st % sx) * 4 + (w16 & 3)) * BROWS;
  const long kofs = (long)blockIdx.z * Kslice;
  const int NT = Kslice >> 6;

  long arow[2], brow[2];
  int  sgel[2], dofs[2];
#pragma unroll
  for (int l = 0; l < 2; ++l) {
    const int g = l * 512 + tid;
    const int row = g >> 2;
    sgel[l] = ((g & 3) ^ ((row >> 1) & 3)) * 8;
    dofs[l] = g * 16;
    arow[l] = (bm + row) * (long)lda + kofs;
    // clamp B source row (dest rows >= BROWS hold dead duplicates, never read)
    const int rb = (row < BROWS) ? row : (BROWS - 1);
    brow[l] = (bn + rb) * (long)ldb + kofs;
  }
  auto stage_half = [&](int h) {
    if (h >= (NT << 2)) return;
    const int th = h >> 2, hi = h & 3, buf = th & 1;
    const int ks = hi >> 1, isA = hi & 1;
    char* db = (char*)&lds[buf][isA ? 0 : 1][0] + ks * 16384;
    const long kb = (long)th * 64 + ks * 32;
#pragma unroll
    for (int l = 0; l < 2; ++l) {
      const short* src = (isA ? A + arow[l] : Bw + brow[l]) + kb + sgel[l];
      lds_load16(src, db + dofs[l]);
    }
  };

  const int xsw = (l4 ^ ((l15 >> 1) & 3)) << 4;
  const int aofs = (wm * 128 + l15) * 64 + xsw;
  const int bofs = (wn * (NF * 16) + l15) * 64 + xsw;

  f32x4 acc[8][NF] = {};
  bf8 fa[4], fa2[4], fb[NF];

#define PH_MID                                             \
  __builtin_amdgcn_s_barrier();                            \
  __builtin_amdgcn_s_setprio(1);
#define PH_END                                             \
  __builtin_amdgcn_s_setprio(0);                           \
  __builtin_amdgcn_s_barrier();                            \
  asm volatile("" ::: "memory");

#pragma unroll
  for (int h = 0; h < 7; ++h) stage_half(h);
  asm volatile("s_waitcnt vmcnt(6)" ::: "memory");
  __builtin_amdgcn_s_barrier();
  asm volatile("" ::: "memory");

  for (int u = 0; u < NT; ++u) {
    const int buf = u & 1;
    const char* pa = (const char*)&lds[buf][0][0];
    const char* pb = (const char*)&lds[buf][1][0];
#pragma unroll
    for (int m = 0; m < 4; ++m) fa[m] = *(const bf8*)(pa + aofs + m * 1024);
#pragma unroll
    for (int n = 0; n < NF; ++n) fb[n] = *(const bf8*)(pb + bofs + n * 1024);
    stage_half(4 * u + 7);
    PH_MID
#pragma unroll
    for (int m = 0; m < 4; ++m)
#pragma unroll
      for (int n = 0; n < NF; ++n)
        acc[m][n] = __builtin_amdgcn_mfma_f32_16x16x32_bf16(fa[m], fb[n], acc[m][n], 0, 0, 0);
    PH_END
#pragma unroll
    for (int m = 0; m < 4; ++m) fa2[m] = *(const bf8*)(pa + aofs + (4 + m) * 1024);
    stage_half(4 * u + 8);
    PH_MID
#pragma unroll
    for (int m = 0; m < 4; ++m)
#pragma unroll
      for (int n = 0; n < NF; ++n)
        acc[4 + m][n] = __builtin_amdgcn_mfma_f32_16x16x32_bf16(fa2[m], fb[n], acc[4 + m][n], 0, 0, 0);
    PH_END
#pragma unroll
    for (int m = 0; m < 4; ++m) fa[m] = *(const bf8*)(pa + 16384 + aofs + m * 1024);
#pragma unroll
    for (int n = 0; n < NF; ++n) fb[n] = *(const bf8*)(pb + 16384 + bofs + n * 1024);
    stage_half(4 * u + 9);
    PH_MID
#pragma unroll
    for (int m = 0; m < 4; ++m)
#pragma unroll
      for (int n = 0; n < NF; ++n)
        acc[m][n] = __builtin_amdgcn_mfma_f32_16x16x32_bf16(fa[m], fb[n], acc[m][n], 0, 0, 0);
    PH_END
#pragma unroll
    for (int m = 0; m < 4; ++m) fa2[m] = *(const bf8*)(pa + 16384 + aofs + (4 + m) * 1024);
    stage_half(4 * u + 10);
    if (u <= NT - 3)      asm volatile("s_waitcnt vmcnt(6)" ::: "memory");
    else if (u == NT - 2) asm volatile("s_waitcnt vmcnt(0)" ::: "memory");
    PH_MID
#pragma unroll
    for (int m = 0; m < 4; ++m)
#pragma unroll
      for (int n = 0; n < NF; ++n)
        acc[4 + m][n] = __builtin_amdgcn_mfma_f32_16x16x32_bf16(fa2[m], fb[n], acc[4 + m][n], 0, 0, 0);
    PH_END
  }
#undef PH_MID
#undef PH_END

  // ---------- epilogue ----------
#pragma unroll
  for (int mg = 0; mg < 8; ++mg)
#pragma unroll
    for (int n = 0; n < NF; ++n) {
      const long col = bn + wn * (NF * 16) + n * 16 + l15;
#pragma unroll
      for (int r = 0; r < 4; ++r) {
        const long row = bm + wm * 128 + mg * 16 + l4 * 4 + r;
        float v = acc[mg][n][r];
        if (EPI == 0) {
          ((short*)Cout)[row * N + col] = to_bf16(v);
        } else if (EPI == 1) {
          ((short*)Cout)[row * N + col] = to_bf16(v / (1.f + __expf(-v)));
        } else {
          ((short*)Cout)[blockIdx.z * zstride + row * N + col] = to_bf16(v);
        }
      }
    }
}

// ---------------- K pack + V pack, one launch ----------------
__global__ __launch_bounds__(256)
void pack_kv(const short* __restrict__ qkv, short* __restrict__ Kp,
             short* __restrict__ Vp) {
  __shared__ short tile[64][72];
  const int bx = blockIdx.x, bh = blockIdx.y;
  const int b = bh >> 4, h = bh & 15;
  const int t = threadIdx.x;
  if (bx < 64) {
    const int g = bx;
    const int row = t >> 3, cc = t & 7, c = cc >> 1, hi = cc & 1;
    const bf8 v = *(const bf8*)&qkv[(long)(b * SEQT + g * 32 + row) * QKLD +
                                    1024 + h * HWID + c * 16 + hi * 8];
    *(bf8*)&Kp[(((long)bh * 256 + g * 4 + c) * 64 + hi * 32 + row) * 8] = v;
  } else {
    const int tc = bx - 64;
    {
      const int r = t >> 2, c = (t & 3) * 16;
      const long src = (long)(b * SEQT + tc * 64 + r) * QKLD + 2048 + h * HWID + c;
      *(bf8*)&tile[r][c]     = *(const bf8*)&qkv[src];
      *(bf8*)&tile[r][c + 8] = *(const bf8*)&qkv[src + 8];
    }
    __syncthreads();
    const int dg = t >> 7, ch = (t >> 5) & 3, row = t & 31;
#pragma unroll
    for (int hi = 0; hi < 2; ++hi) {
      short o[8];
#pragma unroll
      for (int j = 0; j < 8; ++j) o[j] = tile[ch * 16 + hi * 8 + j][dg * 32 + row];
      *(bf8*)&Vp[(((long)bh * 256 + dg * 128 + tc * 4 + ch) * 64 + hi * 32 + row) * 8] =
          *(bf8*)o;
    }
  }
}

// ---------------- Flash attention (R15 exact): K dbuf, V same-iter ----------
__global__ __launch_bounds__(64, 2)
void attn_kernel(const short* __restrict__ qkv, const short* __restrict__ Kp,
                 const short* __restrict__ Vp, const short* __restrict__ xn,
                 float* __restrict__ att) {
  const int L = blockIdx.x;
  const int bh = (L & 7) * 4 + ((L >> 3) & 3);
  const int u = L >> 5;
  const int qtile = (u < 32) ? (63 - u) : (u - 32);   // pair heavy+light per SIMD
  const int b = bh >> 4, h = bh & 15;
  const int q0 = qtile * 32;
  const int lane = threadIdx.x;
  const int l31 = lane & 31, hi = lane >> 5;
  const long tokbase = (long)b * SEQT;

  bf8 qf[4];
  {
    const short* qrow = qkv + (tokbase + q0 + l31) * QKLD + h * HWID + hi * 8;
#pragma unroll
    for (int c = 0; c < 4; ++c) qf[c] = *(const bf8*)(qrow + c * 16);
  }

  const float slope2 = exp2f(-0.5f * (float)(h + 1)) * 1.44269504f;
  const float sc2 = 0.125f * 1.44269504f;
  float arr[16];
#pragma unroll
  for (int r = 0; r < 16; ++r) arr[r] = slope2 * (float)((r & 3) + 8 * (r >> 2));
  const float hofs = slope2 * 4.f * (float)hi;
  const float qabs = (float)(q0 + l31);

  float m2 = -1e30f, lsum = 0.f;
  f32x16 acc0 = {}, acc1 = {};
  const int ktm = q0 >> 6;
  const bf8* kfb = (const bf8*)Kp + (long)bh * 16384 + lane;
  const bf8* vfb = (const bf8*)Vp + (long)bh * 16384 + lane;

  bf8 kc[8], kn[8], vc[8];
#pragma unroll
  for (int c = 0; c < 4; ++c) {
    kc[c]     = kfb[c * 64];
    kc[4 + c] = kfb[256 + c * 64];
  }

#pragma unroll 2
  for (int kt = 0; kt <= ktm; ++kt) {
    const int k0 = kt * 64;
    const long vb = (long)kt * 256;
#pragma unroll
    for (int ch = 0; ch < 4; ++ch) {
      vc[ch]     = vfb[vb + ch * 64];
      vc[4 + ch] = vfb[8192 + vb + ch * 64];
    }
    const long nb = (long)(kt < ktm ? kt + 1 : kt) * 512;
#pragma unroll
    for (int c = 0; c < 4; ++c) {
      kn[c]     = kfb[nb + c * 64];
      kn[4 + c] = kfb[nb + 256 + c * 64];
    }
    f32x16 s0 = {}, s1 = {};
#pragma unroll
    for (int c = 0; c < 4; ++c) {
      s0 = __builtin_amdgcn_mfma_f32_32x32x16_bf16(kc[c], qf[c], s0, 0, 0, 0);
      s1 = __builtin_amdgcn_mfma_f32_32x32x16_bf16(kc[4 + c], qf[c], s1, 0, 0, 0);
    }
    const float base = slope2 * ((float)k0 - qabs) + hofs;
    float s[32];
#pragma unroll
    for (int r = 0; r < 16; ++r) {
      s[r]      = fmaf(s0[r], sc2, base + arr[r]);
      s[16 + r] = fmaf(s1[r], sc2, base + arr[r] + slope2 * 32.f);
    }
    if (kt == ktm) {
      const int qi = q0 + l31;
#pragma unroll
      for (int r = 0; r < 16; ++r) {
        const int krel = (r & 3) + 8 * (r >> 2) + 4 * hi;
        if (k0 + krel > qi)      s[r]      = -1e30f;
        if (k0 + 32 + krel > qi) s[16 + r] = -1e30f;
      }
    }
    float ma = s[0], mb = s[1], mc = s[2], md = s[3];
#pragma unroll
    for (int i = 4; i < 32; i += 4) {
      ma = fmaxf(ma, s[i]); mb = fmaxf(mb, s[i + 1]);
      mc = fmaxf(mc, s[i + 2]); md = fmaxf(md, s[i + 3]);
    }
    float pm = fmaxf(fmaxf(ma, mb), fmaxf(mc, md));
    pm = fmaxf(pm, __shfl_xor(pm, 32));
    if (!__all(pm - m2 <= 11.0f)) {
      const float nm = fmaxf(m2, pm);
      const float alpha = exp2_fast(m2 - nm);
      m2 = nm;
      lsum *= alpha;
      acc0 *= alpha;
      acc1 *= alpha;
    }
    float p[32];
#pragma unroll
    for (int i = 0; i < 32; ++i) p[i] = exp2_fast(s[i] - m2);
    float sa = p[0], sb = p[1], sc = p[2], sd = p[3];
#pragma unroll
    for (int i = 4; i < 32; i += 4) {
      sa += p[i]; sb += p[i + 1]; sc += p[i + 2]; sd += p[i + 3];
    }
    float rs = (sa + sb) + (sc + sd);
    rs += __shfl_xor(rs, 32);
    lsum += rs;
    unsigned cpk[16];
#pragma unroll
    for (int g = 0; g < 8; ++g) {
      cpk[g]     = cvt_pk_bf16(p[2 * g], p[2 * g + 1]);
      cpk[8 + g] = cvt_pk_bf16(p[16 + 2 * g], p[16 + 2 * g + 1]);
    }
    bf8 pb[4];
#pragma unroll
    for (int ch = 0; ch < 4; ++ch) {
      const int cb = (ch >> 1) * 8 + (ch & 1) * 4;
      unsigned u0 = cpk[cb + 0], u2 = cpk[cb + 2];
      unsigned u1 = cpk[cb + 1], u3 = cpk[cb + 3];
      asm("v_permlane32_swap_b32 %0, %1" : "+v"(u0), "+v"(u2));
      asm("v_permlane32_swap_b32 %0, %1" : "+v"(u1), "+v"(u3));
      union { unsigned u[4]; bf8 v; } f;
      f.u[0] = u0; f.u[1] = u1; f.u[2] = u2; f.u[3] = u3;
      pb[ch] = f.v;
    }
#pragma unroll
    for (int ch = 0; ch < 4; ++ch) {
      acc0 = __builtin_amdgcn_mfma_f32_32x32x16_bf16(vc[ch], pb[ch], acc0, 0, 0, 0);
      acc1 = __builtin_amdgcn_mfma_f32_32x32x16_bf16(vc[4 + ch], pb[ch], acc1, 0, 0, 0);
    }
#pragma unroll
    for (int i = 0; i < 8; ++i) kc[i] = kn[i];
  }

  __shared__ float Os[32 * 68];
  const float rl = 1.f / lsum;
#pragma unroll
  for (int r = 0; r < 16; ++r) {
    const int d0 = (r & 3) + 8 * (r >> 2) + 4 * hi;
    Os[l31 * 68 + d0]      = acc0[r] * rl;
    Os[l31 * 68 + 32 + d0] = acc1[r] * rl;
  }
  __syncthreads();
#pragma unroll
  for (int it = 0; it < 8; ++it) {
    const int idx = it * 64 + lane;
    const int row = idx >> 4, c4 = idx & 15;
    const float4 ov = *(const float4*)&Os[row * 68 + c4 * 4];
    const long gbase = (tokbase + q0 + row) * DMODEL + h * HWID + c4 * 4;
    const short4 xv = *(const short4*)&xn[gbase];
    float4 o;
    o.x = ov.x + from_bf16(xv.x);
    o.y = ov.y + from_bf16(xv.y);
    o.z = ov.z + from_bf16(xv.z);
    o.w = ov.w + from_bf16(xv.w);
    *(float4*)&att[gbase] = o;
  }
}

// ---------------- combine: d_out += sum of 4 split-K bf16 partials ----------
__global__ __launch_bounds__(256)
void combine_kernel(const short* __restrict__ p, float* __restrict__ dout, int n4) {
  int i = blockIdx.x * 256 + threadIdx.x;
  if (i < n4) {
    float4 a = ((const float4*)dout)[i];
    short4 b0 = ((const short4*)(p))[i];
    short4 b1 = ((const short4*)(p + 4194304))[i];
    short4 b2 = ((const short4*)(p + 8388608))[i];
    short4 b3 = ((const short4*)(p + 12582912))[i];
    a.x += (from_bf16(b0.x) + from_bf16(b1.x)) + (from_bf16(b2.x) + from_bf16(b3.x));
    a.y += (from_bf16(b0.y) + from_bf16(b1.y)) + (from_bf16(b2.y) + from_bf16(b3.y));
    a.z += (from_bf16(b0.z) + from_bf16(b1.z)) + (from_bf16(b2.z) + from_bf16(b3.z));
    a.w += (from_bf16(b0.w) + from_bf16(b1.w)) + (from_bf16(b2.w) + from_bf16(b3.w));
    ((float4*)dout)[i] = a;
  }
}

// ---------------- launcher ----------------
extern "C" void kernel_launch(void* const* d_in, const int* in_sizes, int n_in,
                              void* d_out, int out_size, void* d_ws, size_t ws_size,
                              hipStream_t stream) {
  (void)in_sizes; (void)n_in; (void)out_size; (void)ws_size;
  const float* x  = (const float*)d_in[0];
  const float* Wq = (const float*)d_in[1];
  const float* Wk = (const float*)d_in[2];
  const float* Wv = (const float*)d_in[3];
  const float* W1 = (const float*)d_in[4];
  const float* W2 = (const float*)d_in[5];
  const float* g1 = (const float*)d_in[6];
  const float* b1 = (const float*)d_in[7];
  const float* g2 = (const float*)d_in[8];
  const float* b2 = (const float*)d_in[9];

  char* ws = (char*)d_ws;
  const size_t MB = 1024 * 1024;
  short* wqkv_b = (short*)(ws + 0);        // 6 MB [3072][1024]
  short* w1_b   = (short*)(ws + 6  * MB);  // 8 MB
  short* w2_b   = (short*)(ws + 14 * MB);  // 8 MB
  short* xn     = (short*)(ws + 22 * MB);  // 8 MB [NTOK][D]
  short* qkv    = (short*)(ws + 30 * MB);  // 24 MB [NTOK][3072]
  short* m1     = (short*)(ws + 22 * MB);  // 32 MB (aliases xn+qkv, dead after attn)
  short* Kp     = (short*)(ws + 54 * MB);  // 8 MB packed K frags (dead after attn)
  short* Vp     = (short*)(ws + 62 * MB);  // 8 MB packed V frags (dead after attn)
  short* hb     = (short*)(ws + 70 * MB);  // 8 MB (dead after mlp1)
  short* parts  = (short*)(ws + 54 * MB);  // 32 MB bf16 (aliases Kp/Vp/hb)
  float* att    = (float*)d_out;           // att lives in d_out (combine residual)

  // fused weight-convert + LN1
  prep_kernel<<<15360, 256, 0, stream>>>(Wq, Wk, Wv, W1, W2, wqkv_b, w1_b, w2_b,
                                         x, g1, b1, xn);

  // fused QKV: [NTOK][3072], BN=192 -> 16x16 = 256 balanced blocks
  gemm256<0, 3><<<dim3(16, 16), 512, 0, stream>>>(xn, wqkv_b, qkv, QKLD, DMODEL,
                                                  DMODEL, DMODEL, 0);
  pack_kv<<<dim3(96, 32), 256, 0, stream>>>(qkv, Kp, Vp);

  attn_kernel<<<2048, 64, 0, stream>>>(qkv, Kp, Vp, xn, att);

  ln_kernel<<<NTOK, 256, 0, stream>>>(att, g2, b2, hb);

  // MLP1: m1 = silu(hb * w1^T)
  gemm256<1, 4><<<dim3(16, 16), 512, 0, stream>>>(hb, w1_b, m1, FFDIM, DMODEL,
                                                  DMODEL, DMODEL, 0);
  // MLP2 split-K=4 into bf16 parts, then combine with att residual (in d_out)
  gemm256<2, 4><<<dim3(4, 16, 4), 512, 0, stream>>>(m1, w2_b, parts, DMODEL, FFDIM,
                                                    FFDIM, 1024, (long)NTOK * DMODEL);
  combine_kernel<<<4096, 256, 0, stream>>>(parts, (float*)d_out, 1048576);
}